// Round 20
// baseline (455.157 us; speedup 1.0000x reference)
//
#include <hip/hip_runtime.h>
#include <stdint.h>

typedef __attribute__((ext_vector_type(8))) short short8;
typedef __attribute__((ext_vector_type(4))) float floatx4;

__device__ __forceinline__ float bf2f(uint16_t u) {
  union { uint32_t u; float f; } c; c.u = (uint32_t)u << 16; return c.f;
}
__device__ __forceinline__ uint16_t f2bf(float f) {
  union { float f; uint32_t u; } c; c.f = f;
  return (uint16_t)((c.u + 0x7fffu + ((c.u >> 16) & 1u)) >> 16);
}
__device__ __forceinline__ void gload_lds16(const void* g, void* l) {
  __builtin_amdgcn_global_load_lds(
      (const __attribute__((address_space(1))) uint32_t*)g,
      (__attribute__((address_space(3))) uint32_t*)l, 16, 0, 0);
}
__device__ __forceinline__ short8 cvt8(const float* src, size_t u) {
  const floatx4* p = (const floatx4*)src + u * 2;
  floatx4 a = p[0], b = p[1];
  short8 o;
  o[0] = (short)f2bf(a[0]); o[1] = (short)f2bf(a[1]);
  o[2] = (short)f2bf(a[2]); o[3] = (short)f2bf(a[3]);
  o[4] = (short)f2bf(b[0]); o[5] = (short)f2bf(b[1]);
  o[6] = (short)f2bf(b[2]); o[7] = (short)f2bf(b[3]);
  return o;
}

// ---- fused convert: x, w_out plain; w_in rows PERMUTED head-major; bias too.
__global__ void k_cvt_all(const float* __restrict__ x, const float* __restrict__ wi,
                          const float* __restrict__ wo, const float* __restrict__ bi,
                          uint16_t* __restrict__ xb, uint16_t* __restrict__ wib,
                          uint16_t* __restrict__ wob, float* __restrict__ bip) {
  const int NX = 4194304, NWI = 393216, NWO = 131072, NB = 384;  // 8-elem units
  int i = blockIdx.x * 256 + threadIdx.x;
  if (i < NX) {
    *((short8*)xb + i) = cvt8(x, i);
  } else if (i < NX + NWI) {
    int j = i - NX;
    int row = j >> 7, cu = j & 127;
    int h = (row & 1023) >> 6, t = row >> 10, d = row & 63;
    int nrow = h * 192 + t * 64 + d;
    *((short8*)wib + (size_t)nrow * 128 + cu) = cvt8(wi, j);
  } else if (i < NX + NWI + NWO) {
    int j = i - NX - NWI;
    *((short8*)wob + j) = cvt8(wo, j);
  } else if (i < NX + NWI + NWO + NB) {
    int j = i - NX - NWI - NWO;
    int b0 = j * 8;
    int h = (b0 & 1023) >> 6, t = b0 >> 10, d = b0 & 63;
    int dst = h * 192 + t * 64 + d;
#pragma unroll
    for (int e = 0; e < 8; e++) bip[dst + e] = bi[b0 + e];
  }
}

// bijective XCD-chunk swizzle + column-fastest decode (block indices)
__device__ __forceinline__ void decode_bid(int bid, int nwg, int ncols,
                                           int* mblk, int* nblk) {
  const int q = nwg >> 3;
  const int wg = (bid & 7) * q + (bid >> 3);
  *nblk = wg % ncols;
  *mblk = wg / ncols;
}

// =============== GEMM1: BM=128 x BN=192, 256 thr, fused attn ================
// T4 pipeline: 3 LDS buffers, depth-2 prefetch, counted vmcnt(5) (never 0
// mid-loop), raw s_barrier (no drain), setprio around MFMA cluster.
// LDS: 3 x (A 8KB + B 12KB) = 60KB; epilogue [128][200] 50KB (union).
__global__ __launch_bounds__(256, 2) void k_gemm_qkv_attn(
    const uint16_t* __restrict__ A, const uint16_t* __restrict__ Wt,
    const float* __restrict__ bias, uint16_t* __restrict__ attn_o,
    int K, int nwg) {
  __shared__ __align__(16) unsigned char lds_raw[61440];
  uint16_t* lds_a  = (uint16_t*)lds_raw;             // 3 x 8KB  (A: 128x32)
  uint16_t* lds_b  = (uint16_t*)(lds_raw + 24576);   // 3 x 12KB (B: 192x32)
  uint16_t* lds_ep = (uint16_t*)lds_raw;             // 50KB epilogue [128][200]

  const int t = threadIdx.x;
  const int wave = t >> 6, lane = t & 63;
  const int wr = wave >> 1, wc = wave & 1;
  int mblk, nblk;
  decode_bid(blockIdx.x, nwg, 16, &mblk, &nblk);
  const int m0 = mblk * 128, n0 = nblk * 192;

  const char* gA = (const char*)(A + (size_t)(m0 + (t >> 2)) * K) + (t & 3) * 16;
  const char* gB = (const char*)(Wt + (size_t)(n0 + (t >> 2)) * K) + (t & 3) * 16;
  const size_t rs64 = (size_t)64 * K * 2;
  const int ksub = lane >> 4, rrow = lane & 15;
  const int nT = K / 32;

  floatx4 acc[4][6];
#pragma unroll
  for (int i = 0; i < 4; i++)
#pragma unroll
    for (int j = 0; j < 6; j++) acc[i][j] = (floatx4){0.f, 0.f, 0.f, 0.f};

  // stage tile into buffer (tile % 3); 5 gloads per wave
  auto stage = [&](int tile, int buf) {
    char* lA = (char*)lds_a + buf * 8192 + wave * 1024;
    char* lB = (char*)lds_b + buf * 12288 + wave * 1024;
    const char* ga = gA + (size_t)tile * 64;
    const char* gb = gB + (size_t)tile * 64;
    gload_lds16(ga, lA);
    gload_lds16(ga + rs64, lA + 4096);
    gload_lds16(gb, lB);
    gload_lds16(gb + rs64, lB + 4096);
    gload_lds16(gb + 2 * rs64, lB + 8192);
  };
  auto compute = [&](int buf) {
    const short8* pa = (const short8*)(lds_a + buf * 4096);
    const short8* pb = (const short8*)(lds_b + buf * 6144);
    short8 af[4], bfr[6];
#pragma unroll
    for (int i = 0; i < 4; i++)
      af[i] = pa[(wr * 64 + i * 16 + rrow) * 4 + ksub];
#pragma unroll
    for (int j = 0; j < 6; j++)
      bfr[j] = pb[(wc * 96 + j * 16 + rrow) * 4 + ksub];
    __builtin_amdgcn_s_setprio(1);
#pragma unroll
    for (int i = 0; i < 4; i++)
#pragma unroll
      for (int j = 0; j < 6; j++)
        acc[i][j] = __builtin_amdgcn_mfma_f32_16x16x32_bf16(af[i], bfr[j], acc[i][j], 0, 0, 0);
    __builtin_amdgcn_s_setprio(0);
  };

  stage(0, 0);
  stage(1, 1);
  int cc = 0;        // compute buffer for tile tt
  int cs = 2;        // stage buffer for tile tt+2
  for (int tt = 0; tt < nT - 1; ++tt) {
    // stage(tt) landed (stage(tt+1)'s 5 loads stay in flight) -- never drain
    asm volatile("s_waitcnt vmcnt(5)" ::: "memory");
    __builtin_amdgcn_s_barrier();
    // by now all waves' reads of buf (tt-1)%3 retired -> safe to overwrite
    if (tt + 2 < nT) stage(tt + 2, cs);
    compute(cc);
    cc = (cc == 2) ? 0 : cc + 1;
    cs = (cs == 2) ? 0 : cs + 1;
  }
  asm volatile("s_waitcnt vmcnt(0)" ::: "memory");
  __builtin_amdgcn_s_barrier();
  compute(cc);
  __syncthreads();   // full drain before epilogue reuses LDS

  // epilogue 1: bias + store C tile to LDS as bf16 [row][200]
  const int cq = lane >> 4, cr = lane & 15;
#pragma unroll
  for (int j = 0; j < 6; j++) {
    int col = wc * 96 + j * 16 + cr;
    float bv = bias[n0 + col];
#pragma unroll
    for (int i = 0; i < 4; i++) {
      int row = wr * 64 + i * 16 + cq * 4;
#pragma unroll
      for (int rg = 0; rg < 4; rg++)
        lds_ep[(size_t)(row + rg) * 200 + col] = f2bf(acc[i][j][rg] + bv);
    }
  }
  __syncthreads();

  // epilogue 2: window attention, 8 lanes per window, 8 windows per wave.
  const int h = nblk;
  const int g8 = lane >> 3, s8 = lane & 7;
  const int r0 = (wave * 8 + g8) * 4;
  float q[4][8], k[4][8], v[4][8];
#pragma unroll
  for (int i = 0; i < 4; i++) {
    const uint16_t* rp = lds_ep + (size_t)(r0 + i) * 200;
    short8 qv = *(const short8*)(rp + s8 * 8);
    short8 kv = *(const short8*)(rp + 64 + s8 * 8);
    short8 vv = *(const short8*)(rp + 128 + s8 * 8);
#pragma unroll
    for (int d = 0; d < 8; d++) {
      q[i][d] = bf2f((uint16_t)qv[d]);
      k[i][d] = bf2f((uint16_t)kv[d]);
      v[i][d] = bf2f((uint16_t)vv[d]);
    }
  }
  float s[4][4];
#pragma unroll
  for (int qi = 0; qi < 4; qi++)
#pragma unroll
    for (int ki = 0; ki < 4; ki++) {
      float a = 0.f;
#pragma unroll
      for (int d = 0; d < 8; d++) a = fmaf(q[qi][d], k[ki][d], a);
      s[qi][ki] = a;
    }
#pragma unroll
  for (int off = 1; off <= 4; off <<= 1)
#pragma unroll
    for (int qi = 0; qi < 4; qi++)
#pragma unroll
      for (int ki = 0; ki < 4; ki++)
        s[qi][ki] += __shfl_xor(s[qi][ki], off, 64);

#pragma unroll
  for (int qi = 0; qi < 4; qi++) {
    float a0 = s[qi][0] * 0.125f, a1 = s[qi][1] * 0.125f;
    float a2 = s[qi][2] * 0.125f, a3 = s[qi][3] * 0.125f;
    float m = fmaxf(fmaxf(a0, a1), fmaxf(a2, a3));
    float e0 = __expf(a0 - m), e1 = __expf(a1 - m);
    float e2 = __expf(a2 - m), e3 = __expf(a3 - m);
    float inv = 1.f / (e0 + e1 + e2 + e3);
    short8 ov;
#pragma unroll
    for (int d = 0; d < 8; d++) {
      float o = (e0 * v[0][d] + e1 * v[1][d] + e2 * v[2][d] + e3 * v[3][d]) * inv;
      ov[d] = (short)f2bf(o);
    }
    *(short8*)(attn_o + (size_t)(m0 + r0 + qi) * 1024 + h * 64 + s8 * 8) = ov;
  }
}

// ---- GEMM 2 mainloop (r11 proven): dbuf 2-phase, 128x128 -------------------
__device__ __forceinline__ void gemm_main(
    const uint16_t* __restrict__ A, const uint16_t* __restrict__ Wt, int K,
    uint16_t* lds_a, uint16_t* lds_b, int m0, int n0, floatx4 acc[4][4]) {
  const int t = threadIdx.x;
  const int wave = t >> 6, lane = t & 63;
  const int wr = wave >> 1, wc = wave & 1;
  const int r = t >> 2;
  const int cb = (t & 3) * 16;
  const char* gA = (const char*)(A + (size_t)(m0 + r) * K) + cb;
  const char* gB = (const char*)(Wt + (size_t)(n0 + r) * K) + cb;
  const size_t rowskip = (size_t)64 * K * 2;
  const int ksub = lane >> 4, rrow = lane & 15;
  const int nT = K / 32;

  {
    char* lA = (char*)lds_a + wave * 1024;
    char* lB = (char*)lds_b + wave * 1024;
    gload_lds16(gA, lA);
    gload_lds16(gA + rowskip, lA + 4096);
    gload_lds16(gB, lB);
    gload_lds16(gB + rowskip, lB + 4096);
    gA += 64; gB += 64;
  }
  __syncthreads();

  int c = 0;
  for (int tt = 0; tt < nT; ++tt) {
    if (tt + 1 < nT) {
      char* lA = (char*)lds_a + (c ^ 1) * 8192 + wave * 1024;
      char* lB = (char*)lds_b + (c ^ 1) * 8192 + wave * 1024;
      gload_lds16(gA, lA);
      gload_lds16(gA + rowskip, lA + 4096);
      gload_lds16(gB, lB);
      gload_lds16(gB + rowskip, lB + 4096);
      gA += 64; gB += 64;
    }
    const short8* pa = (const short8*)(lds_a + c * 4096);
    const short8* pb = (const short8*)(lds_b + c * 4096);
    short8 af[4], bfr[4];
#pragma unroll
    for (int i = 0; i < 4; i++)
      af[i] = pa[(wr * 64 + i * 16 + rrow) * 4 + ksub];
#pragma unroll
    for (int j = 0; j < 4; j++)
      bfr[j] = pb[(wc * 64 + j * 16 + rrow) * 4 + ksub];
#pragma unroll
    for (int i = 0; i < 4; i++)
#pragma unroll
      for (int j = 0; j < 4; j++)
        acc[i][j] = __builtin_amdgcn_mfma_f32_16x16x32_bf16(af[i], bfr[j], acc[i][j], 0, 0, 0);
    __syncthreads();
    c ^= 1;
  }
}

// ---- GEMM 2: y = x_bf + gate*(attn_bf @ W_out^T + b_out), bf16 y -----------
__global__ __launch_bounds__(256, 2) void k_gemm_out(
    const uint16_t* __restrict__ A, const uint16_t* __restrict__ Wt,
    const float* __restrict__ bias, const uint16_t* __restrict__ xres_bf,
    const float* __restrict__ gate, uint16_t* __restrict__ Y,
    int K, int N, int nwg, int ncols) {
  __shared__ __align__(16) uint16_t lds_a[2 * 128 * 32];
  __shared__ __align__(16) uint16_t lds_b[2 * 128 * 32];
  floatx4 acc[4][4];
#pragma unroll
  for (int i = 0; i < 4; i++)
#pragma unroll
    for (int j = 0; j < 4; j++) acc[i][j] = (floatx4){0.f, 0.f, 0.f, 0.f};
  int mblk, nblk;
  decode_bid(blockIdx.x, nwg, ncols, &mblk, &nblk);
  const int m0 = mblk * 128, n0 = nblk * 128;
  gemm_main(A, Wt, K, lds_a, lds_b, m0, n0, acc);
  const float g = gate[0];
  const int wave = threadIdx.x >> 6, lane = threadIdx.x & 63;
  const int wr = wave >> 1, wc = wave & 1;
  const int cq = lane >> 4, cr = lane & 15;
#pragma unroll
  for (int j = 0; j < 4; j++) {
    int col = n0 + wc * 64 + j * 16 + cr;
    float bv = bias[col];
#pragma unroll
    for (int i = 0; i < 4; i++) {
      int row = m0 + wr * 64 + i * 16 + cq * 4;
#pragma unroll
      for (int rg = 0; rg < 4; rg++) {
        float o = acc[i][j][rg] + bv;
        float xv = bf2f(xres_bf[(size_t)(row + rg) * N + col]);
        Y[(size_t)(row + rg) * N + col] = f2bf(xv + g * o);
      }
    }
  }
}

// ---- LayerNorm over D=1024, one wave per row; bf16 in -> f32 OUT -----------
__global__ __launch_bounds__(256) void k_ln(
    const uint16_t* __restrict__ y, const float* __restrict__ gamma,
    const float* __restrict__ beta, float* __restrict__ out) {
  const int wave = threadIdx.x >> 6, lane = threadIdx.x & 63;
  const size_t row = (size_t)blockIdx.x * 4 + wave;
  const uint16_t* py = y + row * 1024 + lane * 16;
  short8 v0 = *(const short8*)py;
  short8 v1 = *(const short8*)(py + 8);
  float f[16];
#pragma unroll
  for (int j = 0; j < 8; j++) {
    f[j] = bf2f((uint16_t)v0[j]);
    f[8 + j] = bf2f((uint16_t)v1[j]);
  }
  float sum = 0.f, sq = 0.f;
#pragma unroll
  for (int j = 0; j < 16; j++) { sum += f[j]; sq += f[j] * f[j]; }
#pragma unroll
  for (int off = 32; off; off >>= 1) {
    sum += __shfl_xor(sum, off, 64);
    sq  += __shfl_xor(sq,  off, 64);
  }
  const float mu = sum * (1.f / 1024.f);
  const float var = sq * (1.f / 1024.f) - mu * mu;
  const float inv = rsqrtf(var + 1e-5f);
  const int c0 = lane * 16;
  float* po = out + row * 1024 + lane * 16;
#pragma unroll
  for (int c = 0; c < 4; c++) {
    floatx4 o;
#pragma unroll
    for (int e = 0; e < 4; e++) {
      int j = c * 4 + e;
      o[e] = (f[j] - mu) * inv * gamma[c0 + j] + beta[c0 + j];
    }
    *(floatx4*)(po + c * 4) = o;
  }
}

extern "C" void kernel_launch(void* const* d_in, const int* in_sizes, int n_in,
                              void* d_out, int out_size, void* d_ws, size_t ws_size,
                              hipStream_t stream) {
  const float* x     = (const float*)d_in[0];
  const float* w_in  = (const float*)d_in[1];
  const float* b_in  = (const float*)d_in[2];
  const float* w_out = (const float*)d_in[3];
  const float* b_out = (const float*)d_in[4];
  const float* gamma = (const float*)d_in[5];
  const float* beta  = (const float*)d_in[6];
  const float* gate  = (const float*)d_in[7];
  float* out = (float*)d_out;   // f32 OUTPUT

  const int M = 32768;  // B*N = 4*8192
  char* ws = (char*)d_ws;
  uint16_t* w_in_bf  = (uint16_t*)ws;                       // 6 MiB (permuted)
  uint16_t* w_out_bf = (uint16_t*)(ws + 6291456);           // 2 MiB
  float*    b_in_p   = (float*)(ws + 8388608);              // 12 KiB (permuted bias)
  uint16_t* x_bf     = (uint16_t*)(ws + 8404992);           // 64 MiB
  uint16_t* attn_bf  = (uint16_t*)(ws + 8404992 + 67108864);            // 64 MiB
  uint16_t* y_bf     = (uint16_t*)(ws + 8404992 + 67108864 + 67108864); // 64 MiB

  k_cvt_all<<<18434, 256, 0, stream>>>(x, w_in, w_out, b_in,
                                       x_bf, w_in_bf, w_out_bf, b_in_p);

  const int nwg1 = (M / 128) * 16;             // 4096, %8==0
  const int nwg2 = (M / 128) * (1024 / 128);   // 2048, %8==0
  k_gemm_qkv_attn<<<nwg1, 256, 0, stream>>>(
      x_bf, w_in_bf, b_in_p, attn_bf, 1024, nwg1);
  k_gemm_out<<<nwg2, 256, 0, stream>>>(
      attn_bf, w_out_bf, b_out, x_bf, gate, y_bf, 1024, 1024, nwg2, 1024 / 128);
  k_ln<<<M / 4, 256, 0, stream>>>(y_bf, gamma, beta, out);
}

// Round 21
// 442.171 us; speedup vs baseline: 1.0294x; 1.0294x over previous
//
#include <hip/hip_runtime.h>
#include <stdint.h>

typedef __attribute__((ext_vector_type(8))) short short8;
typedef __attribute__((ext_vector_type(4))) float floatx4;

__device__ __forceinline__ float bf2f(uint16_t u) {
  union { uint32_t u; float f; } c; c.u = (uint32_t)u << 16; return c.f;
}
__device__ __forceinline__ uint16_t f2bf(float f) {
  union { float f; uint32_t u; } c; c.f = f;
  return (uint16_t)((c.u + 0x7fffu + ((c.u >> 16) & 1u)) >> 16);
}
__device__ __forceinline__ void gload_lds16(const void* g, void* l) {
  __builtin_amdgcn_global_load_lds(
      (const __attribute__((address_space(1))) uint32_t*)g,
      (__attribute__((address_space(3))) uint32_t*)l, 16, 0, 0);
}
__device__ __forceinline__ short8 cvt8(const float* src, size_t u) {
  const floatx4* p = (const floatx4*)src + u * 2;
  floatx4 a = p[0], b = p[1];
  short8 o;
  o[0] = (short)f2bf(a[0]); o[1] = (short)f2bf(a[1]);
  o[2] = (short)f2bf(a[2]); o[3] = (short)f2bf(a[3]);
  o[4] = (short)f2bf(b[0]); o[5] = (short)f2bf(b[1]);
  o[6] = (short)f2bf(b[2]); o[7] = (short)f2bf(b[3]);
  return o;
}

// ---- fused convert: x, w_out plain; w_in rows PERMUTED head-major; bias too.
__global__ void k_cvt_all(const float* __restrict__ x, const float* __restrict__ wi,
                          const float* __restrict__ wo, const float* __restrict__ bi,
                          uint16_t* __restrict__ xb, uint16_t* __restrict__ wib,
                          uint16_t* __restrict__ wob, float* __restrict__ bip) {
  const int NX = 4194304, NWI = 393216, NWO = 131072, NB = 384;  // 8-elem units
  int i = blockIdx.x * 256 + threadIdx.x;
  if (i < NX) {
    *((short8*)xb + i) = cvt8(x, i);
  } else if (i < NX + NWI) {
    int j = i - NX;
    int row = j >> 7, cu = j & 127;
    int h = (row & 1023) >> 6, t = row >> 10, d = row & 63;
    int nrow = h * 192 + t * 64 + d;
    *((short8*)wib + (size_t)nrow * 128 + cu) = cvt8(wi, j);
  } else if (i < NX + NWI + NWO) {
    int j = i - NX - NWI;
    *((short8*)wob + j) = cvt8(wo, j);
  } else if (i < NX + NWI + NWO + NB) {
    int j = i - NX - NWI - NWO;
    int b0 = j * 8;
    int h = (b0 & 1023) >> 6, t = b0 >> 10, d = b0 & 63;
    int dst = h * 192 + t * 64 + d;
#pragma unroll
    for (int e = 0; e < 8; e++) bip[dst + e] = bi[b0 + e];
  }
}

// bijective XCD-chunk swizzle + column-fastest decode (block indices)
__device__ __forceinline__ void decode_bid(int bid, int nwg, int ncols,
                                           int* mblk, int* nblk) {
  const int q = nwg >> 3;
  const int wg = (bid & 7) * q + (bid >> 3);
  *nblk = wg % ncols;
  *mblk = wg / ncols;
}

// =============== GEMM1 (r14 proven): BM=128 x BN=192, 256 thr, fused attn ===
// 4 waves (2x2), wave = 64x96 = 4x6 frags of 16x16x32.
// LDS: dbuf A 2x8KB + B 2x12KB = 40KB; epilogue [128][200] 50KB (union).
__global__ __launch_bounds__(256, 3) void k_gemm_qkv_attn(
    const uint16_t* __restrict__ A, const uint16_t* __restrict__ Wt,
    const float* __restrict__ bias, uint16_t* __restrict__ attn_o,
    int K, int nwg) {
  __shared__ __align__(16) unsigned char lds_raw[51200];
  uint16_t* lds_a  = (uint16_t*)lds_raw;             // dbuf 2 x 8KB
  uint16_t* lds_b  = (uint16_t*)(lds_raw + 16384);   // dbuf 2 x 12KB (ends 40KB)
  uint16_t* lds_ep = (uint16_t*)lds_raw;             // 50KB epilogue [128][200]

  const int t = threadIdx.x;
  const int wave = t >> 6, lane = t & 63;
  const int wr = wave >> 1, wc = wave & 1;
  int mblk, nblk;
  decode_bid(blockIdx.x, nwg, 16, &mblk, &nblk);
  const int m0 = mblk * 128, n0 = nblk * 192;

  const char* gA = (const char*)(A + (size_t)(m0 + (t >> 2)) * K) + (t & 3) * 16;
  const char* gB = (const char*)(Wt + (size_t)(n0 + (t >> 2)) * K) + (t & 3) * 16;
  const size_t rs64 = (size_t)64 * K * 2;
  const int ksub = lane >> 4, rrow = lane & 15;
  const int nT = K / 32;

  floatx4 acc[4][6];
#pragma unroll
  for (int i = 0; i < 4; i++)
#pragma unroll
    for (int j = 0; j < 6; j++) acc[i][j] = (floatx4){0.f, 0.f, 0.f, 0.f};

  auto stage = [&](int tile) {
    char* lA = (char*)lds_a + (tile & 1) * 8192 + wave * 1024;
    char* lB = (char*)lds_b + (tile & 1) * 12288 + wave * 1024;
    const char* ga = gA + (size_t)tile * 64;
    const char* gb = gB + (size_t)tile * 64;
    gload_lds16(ga, lA);
    gload_lds16(ga + rs64, lA + 4096);
    gload_lds16(gb, lB);
    gload_lds16(gb + rs64, lB + 4096);
    gload_lds16(gb + 2 * rs64, lB + 8192);
  };

  stage(0);
  __syncthreads();
  for (int tt = 0; tt < nT; ++tt) {
    if (tt + 1 < nT) stage(tt + 1);
    const short8* pa = (const short8*)(lds_a + (tt & 1) * 4096);
    const short8* pb = (const short8*)(lds_b + (tt & 1) * 6144);
    short8 af[4], bfr[6];
#pragma unroll
    for (int i = 0; i < 4; i++)
      af[i] = pa[(wr * 64 + i * 16 + rrow) * 4 + ksub];
#pragma unroll
    for (int j = 0; j < 6; j++)
      bfr[j] = pb[(wc * 96 + j * 16 + rrow) * 4 + ksub];
#pragma unroll
    for (int i = 0; i < 4; i++)
#pragma unroll
      for (int j = 0; j < 6; j++)
        acc[i][j] = __builtin_amdgcn_mfma_f32_16x16x32_bf16(af[i], bfr[j], acc[i][j], 0, 0, 0);
    __syncthreads();
  }

  // epilogue 1: bias + store C tile to LDS as bf16 [row][200]
  const int cq = lane >> 4, cr = lane & 15;
#pragma unroll
  for (int j = 0; j < 6; j++) {
    int col = wc * 96 + j * 16 + cr;
    float bv = bias[n0 + col];
#pragma unroll
    for (int i = 0; i < 4; i++) {
      int row = wr * 64 + i * 16 + cq * 4;
#pragma unroll
      for (int rg = 0; rg < 4; rg++)
        lds_ep[(size_t)(row + rg) * 200 + col] = f2bf(acc[i][j][rg] + bv);
    }
  }
  __syncthreads();

  // epilogue 2: window attention, 8 lanes per window, 8 windows per wave.
  const int h = nblk;
  const int g8 = lane >> 3, s8 = lane & 7;
  const int r0 = (wave * 8 + g8) * 4;
  float q[4][8], k[4][8], v[4][8];
#pragma unroll
  for (int i = 0; i < 4; i++) {
    const uint16_t* rp = lds_ep + (size_t)(r0 + i) * 200;
    short8 qv = *(const short8*)(rp + s8 * 8);
    short8 kv = *(const short8*)(rp + 64 + s8 * 8);
    short8 vv = *(const short8*)(rp + 128 + s8 * 8);
#pragma unroll
    for (int d = 0; d < 8; d++) {
      q[i][d] = bf2f((uint16_t)qv[d]);
      k[i][d] = bf2f((uint16_t)kv[d]);
      v[i][d] = bf2f((uint16_t)vv[d]);
    }
  }
  float s[4][4];
#pragma unroll
  for (int qi = 0; qi < 4; qi++)
#pragma unroll
    for (int ki = 0; ki < 4; ki++) {
      float a = 0.f;
#pragma unroll
      for (int d = 0; d < 8; d++) a = fmaf(q[qi][d], k[ki][d], a);
      s[qi][ki] = a;
    }
#pragma unroll
  for (int off = 1; off <= 4; off <<= 1)
#pragma unroll
    for (int qi = 0; qi < 4; qi++)
#pragma unroll
      for (int ki = 0; ki < 4; ki++)
        s[qi][ki] += __shfl_xor(s[qi][ki], off, 64);

#pragma unroll
  for (int qi = 0; qi < 4; qi++) {
    float a0 = s[qi][0] * 0.125f, a1 = s[qi][1] * 0.125f;
    float a2 = s[qi][2] * 0.125f, a3 = s[qi][3] * 0.125f;
    float m = fmaxf(fmaxf(a0, a1), fmaxf(a2, a3));
    float e0 = __expf(a0 - m), e1 = __expf(a1 - m);
    float e2 = __expf(a2 - m), e3 = __expf(a3 - m);
    float inv = 1.f / (e0 + e1 + e2 + e3);
    short8 ov;
#pragma unroll
    for (int d = 0; d < 8; d++) {
      float o = (e0 * v[0][d] + e1 * v[1][d] + e2 * v[2][d] + e3 * v[3][d]) * inv;
      ov[d] = (short)f2bf(o);
    }
    *(short8*)(attn_o + (size_t)(m0 + r0 + qi) * 1024 + h * 64 + s8 * 8) = ov;
  }
}

// ---- GEMM 2 mainloop (r11 proven): dbuf 2-phase, 128x128 -------------------
__device__ __forceinline__ void gemm_main(
    const uint16_t* __restrict__ A, const uint16_t* __restrict__ Wt, int K,
    uint16_t* lds_a, uint16_t* lds_b, int m0, int n0, floatx4 acc[4][4]) {
  const int t = threadIdx.x;
  const int wave = t >> 6, lane = t & 63;
  const int wr = wave >> 1, wc = wave & 1;
  const int r = t >> 2;
  const int cb = (t & 3) * 16;
  const char* gA = (const char*)(A + (size_t)(m0 + r) * K) + cb;
  const char* gB = (const char*)(Wt + (size_t)(n0 + r) * K) + cb;
  const size_t rowskip = (size_t)64 * K * 2;
  const int ksub = lane >> 4, rrow = lane & 15;
  const int nT = K / 32;

  {
    char* lA = (char*)lds_a + wave * 1024;
    char* lB = (char*)lds_b + wave * 1024;
    gload_lds16(gA, lA);
    gload_lds16(gA + rowskip, lA + 4096);
    gload_lds16(gB, lB);
    gload_lds16(gB + rowskip, lB + 4096);
    gA += 64; gB += 64;
  }
  __syncthreads();

  int c = 0;
  for (int tt = 0; tt < nT; ++tt) {
    if (tt + 1 < nT) {
      char* lA = (char*)lds_a + (c ^ 1) * 8192 + wave * 1024;
      char* lB = (char*)lds_b + (c ^ 1) * 8192 + wave * 1024;
      gload_lds16(gA, lA);
      gload_lds16(gA + rowskip, lA + 4096);
      gload_lds16(gB, lB);
      gload_lds16(gB + rowskip, lB + 4096);
      gA += 64; gB += 64;
    }
    const short8* pa = (const short8*)(lds_a + c * 4096);
    const short8* pb = (const short8*)(lds_b + c * 4096);
    short8 af[4], bfr[4];
#pragma unroll
    for (int i = 0; i < 4; i++)
      af[i] = pa[(wr * 64 + i * 16 + rrow) * 4 + ksub];
#pragma unroll
    for (int j = 0; j < 4; j++)
      bfr[j] = pb[(wc * 64 + j * 16 + rrow) * 4 + ksub];
#pragma unroll
    for (int i = 0; i < 4; i++)
#pragma unroll
      for (int j = 0; j < 4; j++)
        acc[i][j] = __builtin_amdgcn_mfma_f32_16x16x32_bf16(af[i], bfr[j], acc[i][j], 0, 0, 0);
    __syncthreads();
    c ^= 1;
  }
}

// ---- GEMM 2: y = x_bf + gate*(attn_bf @ W_out^T + b_out), bf16 y -----------
__global__ __launch_bounds__(256, 2) void k_gemm_out(
    const uint16_t* __restrict__ A, const uint16_t* __restrict__ Wt,
    const float* __restrict__ bias, const uint16_t* __restrict__ xres_bf,
    const float* __restrict__ gate, uint16_t* __restrict__ Y,
    int K, int N, int nwg, int ncols) {
  __shared__ __align__(16) uint16_t lds_a[2 * 128 * 32];
  __shared__ __align__(16) uint16_t lds_b[2 * 128 * 32];
  floatx4 acc[4][4];
#pragma unroll
  for (int i = 0; i < 4; i++)
#pragma unroll
    for (int j = 0; j < 4; j++) acc[i][j] = (floatx4){0.f, 0.f, 0.f, 0.f};
  int mblk, nblk;
  decode_bid(blockIdx.x, nwg, ncols, &mblk, &nblk);
  const int m0 = mblk * 128, n0 = nblk * 128;
  gemm_main(A, Wt, K, lds_a, lds_b, m0, n0, acc);
  const float g = gate[0];
  const int wave = threadIdx.x >> 6, lane = threadIdx.x & 63;
  const int wr = wave >> 1, wc = wave & 1;
  const int cq = lane >> 4, cr = lane & 15;
#pragma unroll
  for (int j = 0; j < 4; j++) {
    int col = n0 + wc * 64 + j * 16 + cr;
    float bv = bias[col];
#pragma unroll
    for (int i = 0; i < 4; i++) {
      int row = m0 + wr * 64 + i * 16 + cq * 4;
#pragma unroll
      for (int rg = 0; rg < 4; rg++) {
        float o = acc[i][j][rg] + bv;
        float xv = bf2f(xres_bf[(size_t)(row + rg) * N + col]);
        Y[(size_t)(row + rg) * N + col] = f2bf(xv + g * o);
      }
    }
  }
}

// ---- LayerNorm over D=1024, one wave per row; bf16 in -> f32 OUT -----------
__global__ __launch_bounds__(256) void k_ln(
    const uint16_t* __restrict__ y, const float* __restrict__ gamma,
    const float* __restrict__ beta, float* __restrict__ out) {
  const int wave = threadIdx.x >> 6, lane = threadIdx.x & 63;
  const size_t row = (size_t)blockIdx.x * 4 + wave;
  const uint16_t* py = y + row * 1024 + lane * 16;
  short8 v0 = *(const short8*)py;
  short8 v1 = *(const short8*)(py + 8);
  float f[16];
#pragma unroll
  for (int j = 0; j < 8; j++) {
    f[j] = bf2f((uint16_t)v0[j]);
    f[8 + j] = bf2f((uint16_t)v1[j]);
  }
  float sum = 0.f, sq = 0.f;
#pragma unroll
  for (int j = 0; j < 16; j++) { sum += f[j]; sq += f[j] * f[j]; }
#pragma unroll
  for (int off = 32; off; off >>= 1) {
    sum += __shfl_xor(sum, off, 64);
    sq  += __shfl_xor(sq,  off, 64);
  }
  const float mu = sum * (1.f / 1024.f);
  const float var = sq * (1.f / 1024.f) - mu * mu;
  const float inv = rsqrtf(var + 1e-5f);
  const int c0 = lane * 16;
  float* po = out + row * 1024 + lane * 16;
#pragma unroll
  for (int c = 0; c < 4; c++) {
    floatx4 o;
#pragma unroll
    for (int e = 0; e < 4; e++) {
      int j = c * 4 + e;
      o[e] = (f[j] - mu) * inv * gamma[c0 + j] + beta[c0 + j];
    }
    *(floatx4*)(po + c * 4) = o;
  }
}

extern "C" void kernel_launch(void* const* d_in, const int* in_sizes, int n_in,
                              void* d_out, int out_size, void* d_ws, size_t ws_size,
                              hipStream_t stream) {
  const float* x     = (const float*)d_in[0];
  const float* w_in  = (const float*)d_in[1];
  const float* b_in  = (const float*)d_in[2];
  const float* w_out = (const float*)d_in[3];
  const float* b_out = (const float*)d_in[4];
  const float* gamma = (const float*)d_in[5];
  const float* beta  = (const float*)d_in[6];
  const float* gate  = (const float*)d_in[7];
  float* out = (float*)d_out;   // f32 OUTPUT

  const int M = 32768;  // B*N = 4*8192
  char* ws = (char*)d_ws;
  uint16_t* w_in_bf  = (uint16_t*)ws;                       // 6 MiB (permuted)
  uint16_t* w_out_bf = (uint16_t*)(ws + 6291456);           // 2 MiB
  float*    b_in_p   = (float*)(ws + 8388608);              // 12 KiB (permuted bias)
  uint16_t* x_bf     = (uint16_t*)(ws + 8404992);           // 64 MiB
  uint16_t* attn_bf  = (uint16_t*)(ws + 8404992 + 67108864);            // 64 MiB
  uint16_t* y_bf     = (uint16_t*)(ws + 8404992 + 67108864 + 67108864); // 64 MiB

  k_cvt_all<<<18434, 256, 0, stream>>>(x, w_in, w_out, b_in,
                                       x_bf, w_in_bf, w_out_bf, b_in_p);

  const int nwg1 = (M / 128) * 16;             // 4096, %8==0
  const int nwg2 = (M / 128) * (1024 / 128);   // 2048, %8==0
  k_gemm_qkv_attn<<<nwg1, 256, 0, stream>>>(
      x_bf, w_in_bf, b_in_p, attn_bf, 1024, nwg1);
  k_gemm_out<<<nwg2, 256, 0, stream>>>(
      attn_bf, w_out_bf, b_out, x_bf, gate, y_bf, 1024, 1024, nwg2, 1024 / 128);
  k_ln<<<M / 4, 256, 0, stream>>>(y_bf, gamma, beta, out);
}